// Round 1
// baseline (34.342 us; speedup 1.0000x reference)
//
#include <hip/hip_runtime.h>
#include <math.h>

namespace {

constexpr int B_ = 4;
constexpr int N_ = 512;
constexpr int D_ = 256;
constexpr int L_ = 128;
constexpr int TI = 8;  // i-rows per block in dist kernel

// xh_t[b][l][n] = sum_d x[b][n][d] * W[l][d]   (transposed projection)
__global__ __launch_bounds__(128) void proj_kernel(
    const float* __restrict__ x, const float* __restrict__ W,
    float* __restrict__ xh_t) {
  const int tid = threadIdx.x;
  const int b = blockIdx.z;
  const int n = blockIdx.y * 128 + tid;
  const int l0 = blockIdx.x * 4;
  const float4* __restrict__ x4 =
      reinterpret_cast<const float4*>(x + (size_t)(b * N_ + n) * D_);
  const float4* __restrict__ W4 = reinterpret_cast<const float4*>(W);
  float acc0 = 0.f, acc1 = 0.f, acc2 = 0.f, acc3 = 0.f;
#pragma unroll 4
  for (int d4 = 0; d4 < D_ / 4; ++d4) {
    const float4 xv = x4[d4];
    const float4 w0 = W4[(l0 + 0) * (D_ / 4) + d4];
    const float4 w1 = W4[(l0 + 1) * (D_ / 4) + d4];
    const float4 w2 = W4[(l0 + 2) * (D_ / 4) + d4];
    const float4 w3 = W4[(l0 + 3) * (D_ / 4) + d4];
    acc0 += xv.x * w0.x + xv.y * w0.y + xv.z * w0.z + xv.w * w0.w;
    acc1 += xv.x * w1.x + xv.y * w1.y + xv.z * w1.z + xv.w * w1.w;
    acc2 += xv.x * w2.x + xv.y * w2.y + xv.z * w2.z + xv.w * w2.w;
    acc3 += xv.x * w3.x + xv.y * w3.y + xv.z * w3.z + xv.w * w3.w;
  }
  float* o = xh_t + (size_t)(b * L_ + l0) * N_ + n;
  o[0 * N_] = acc0;
  o[1 * N_] = acc1;
  o[2 * N_] = acc2;
  o[3 * N_] = acc3;
}

// Fused: L1 distance vs a-weights + mask, leaky-relu, row softmax with adj.
// Block = (b, i-tile of 8 rows), 512 threads = one j column each.
__global__ __launch_bounds__(512) void dist_softmax_kernel(
    const float* __restrict__ xh_t, const float* __restrict__ adj,
    const int* __restrict__ box_num, const float* __restrict__ a,
    float* __restrict__ out) {
  const int j = threadIdx.x;
  const int i0 = blockIdx.x * TI;
  const int b = blockIdx.y;
  const int bn = box_num[b];

  const float* __restrict__ xh_b = xh_t + (size_t)b * L_ * N_;
  float acc[TI];
#pragma unroll
  for (int r = 0; r < TI; ++r) acc[r] = 0.f;
  float sum_a = 0.f;

#pragma unroll 4
  for (int l = 0; l < L_; ++l) {
    const float* __restrict__ row = xh_b + l * N_;
    const float xj = row[j];     // coalesced vector load
    const float al = a[l];       // uniform -> scalar load
    sum_a += al;
#pragma unroll
    for (int r = 0; r < TI; ++r) {
      // row[i0+r] is wave-uniform -> s_load_dwordx8 expected
      acc[r] += fabsf(row[i0 + r] - xj) * al;
    }
  }

  const bool vj = j < bn;
  float val[TI];
#pragma unroll
  for (int r = 0; r < TI; ++r) {
    const bool vi = (i0 + r) < bn;
    const float d = acc[r] - ((vi && vj) ? 0.f : sum_a);  // + mask*sum(a)
    val[r] = d >= 0.f ? d : 0.01f * d;                    // leaky_relu
  }

  __shared__ float red[8][TI];
  __shared__ float rmax_s[TI];
  __shared__ float rsinv_s[TI];
  const int lane = j & 63;
  const int wid = j >> 6;

  // ---- row max over 512 j ----
  {
    float wm[TI];
#pragma unroll
    for (int r = 0; r < TI; ++r) {
      float m = val[r];
#pragma unroll
      for (int off = 1; off < 64; off <<= 1) m = fmaxf(m, __shfl_xor(m, off));
      wm[r] = m;
    }
    if (lane == 0) {
#pragma unroll
      for (int r = 0; r < TI; ++r) red[wid][r] = wm[r];
    }
  }
  __syncthreads();
  if (j < TI) {
    float m = red[0][j];
#pragma unroll
    for (int w = 1; w < 8; ++w) m = fmaxf(m, red[w][j]);
    rmax_s[j] = m;
  }
  __syncthreads();

  float e[TI];
  const float* __restrict__ adjp = adj + ((size_t)(b * N_ + i0)) * N_ + j;
#pragma unroll
  for (int r = 0; r < TI; ++r) {
    e[r] = adjp[(size_t)r * N_] * expf(val[r] - rmax_s[r]);
  }

  // ---- row sum over 512 j ----
  {
    float wsum[TI];
#pragma unroll
    for (int r = 0; r < TI; ++r) {
      float s = e[r];
#pragma unroll
      for (int off = 1; off < 64; off <<= 1) s += __shfl_xor(s, off);
      wsum[r] = s;
    }
    if (lane == 0) {
#pragma unroll
      for (int r = 0; r < TI; ++r) red[wid][r] = wsum[r];
    }
  }
  __syncthreads();
  if (j < TI) {
    float s = red[0][j];
#pragma unroll
    for (int w = 1; w < 8; ++w) s += red[w][j];
    rsinv_s[j] = 1.0f / s;
  }
  __syncthreads();

  float* __restrict__ op = out + ((size_t)(b * N_ + i0)) * N_ + j;
#pragma unroll
  for (int r = 0; r < TI; ++r) {
    op[(size_t)r * N_] = e[r] * rsinv_s[r] + 1e-10f;
  }
}

}  // namespace

extern "C" void kernel_launch(void* const* d_in, const int* in_sizes, int n_in,
                              void* d_out, int out_size, void* d_ws,
                              size_t ws_size, hipStream_t stream) {
  const float* x = (const float*)d_in[0];        // (B,N,D) f32
  const float* adj = (const float*)d_in[1];      // (B,N,N) f32
  const int* box_num = (const int*)d_in[2];      // (B,1) int32
  const float* W = (const float*)d_in[3];        // (L,D) f32
  const float* a = (const float*)d_in[4];        // (L,) f32
  float* out = (float*)d_out;                    // (B,N,N) f32
  float* xh_t = (float*)d_ws;                    // B*L*N floats = 1 MB scratch

  dim3 g1(L_ / 4, N_ / 128, B_);
  proj_kernel<<<g1, 128, 0, stream>>>(x, W, xh_t);

  dim3 g2(N_ / TI, B_);
  dist_softmax_kernel<<<g2, 512, 0, stream>>>(xh_t, adj, box_num, a, out);
}

// Round 2
// 29.873 us; speedup vs baseline: 1.1496x; 1.1496x over previous
//
#include <hip/hip_runtime.h>
#include <math.h>

namespace {

constexpr int B_ = 4;
constexpr int N_ = 512;
constexpr int D_ = 256;
constexpr int L_ = 128;
constexpr int TI = 4;  // i-rows per block in dist kernel

// xs[b][l][n] = a[l] * sum_d x[b][n][d] * W[l][d]   (transposed, a-scaled)
__global__ __launch_bounds__(128) void proj_kernel(
    const float* __restrict__ x, const float* __restrict__ W,
    const float* __restrict__ a, float* __restrict__ xs) {
  const int tid = threadIdx.x;
  const int b = blockIdx.z;
  const int n = blockIdx.y * 128 + tid;
  const int l0 = blockIdx.x * 4;
  const float4* __restrict__ x4 =
      reinterpret_cast<const float4*>(x + (size_t)(b * N_ + n) * D_);
  const float4* __restrict__ W4 = reinterpret_cast<const float4*>(W);
  float acc0 = 0.f, acc1 = 0.f, acc2 = 0.f, acc3 = 0.f;
#pragma unroll 4
  for (int d4 = 0; d4 < D_ / 4; ++d4) {
    const float4 xv = x4[d4];
    const float4 w0 = W4[(l0 + 0) * (D_ / 4) + d4];
    const float4 w1 = W4[(l0 + 1) * (D_ / 4) + d4];
    const float4 w2 = W4[(l0 + 2) * (D_ / 4) + d4];
    const float4 w3 = W4[(l0 + 3) * (D_ / 4) + d4];
    acc0 += xv.x * w0.x + xv.y * w0.y + xv.z * w0.z + xv.w * w0.w;
    acc1 += xv.x * w1.x + xv.y * w1.y + xv.z * w1.z + xv.w * w1.w;
    acc2 += xv.x * w2.x + xv.y * w2.y + xv.z * w2.z + xv.w * w2.w;
    acc3 += xv.x * w3.x + xv.y * w3.y + xv.z * w3.z + xv.w * w3.w;
  }
  float* o = xs + (size_t)(b * L_ + l0) * N_ + n;
  o[0 * N_] = acc0 * a[l0 + 0];
  o[1 * N_] = acc1 * a[l0 + 1];
  o[2 * N_] = acc2 * a[l0 + 2];
  o[3 * N_] = acc3 * a[l0 + 3];
}

// Fused: L1 distance (a pre-folded) + mask, leaky-relu, row softmax with adj.
// Block = (b, i-tile of TI rows), 512 threads = one j column each.
__global__ __launch_bounds__(512) void dist_softmax_kernel(
    const float* __restrict__ xs, const float* __restrict__ adj,
    const int* __restrict__ box_num, const float* __restrict__ a,
    float* __restrict__ out) {
  const int t = threadIdx.x;
  const int j = t;
  const int i0 = blockIdx.x * TI;
  const int b = blockIdx.y;
  const int bn = box_num[b];
  const float* __restrict__ xs_b = xs + (size_t)b * L_ * N_;

  __shared__ float xi_l[L_ * TI];  // [l][r], 2 KB, read as broadcast float4
  __shared__ float red[8][TI];
  __shared__ float sa_l[2];
  __shared__ float rmax_s[TI];
  __shared__ float rsinv_s[TI];

  // stage i-rows: thread t -> (l = t>>2, r = t&3); 16B-granular gather, once
  xi_l[t] = xs_b[(t >> 2) * N_ + i0 + (t & 3)];

  // sum(a) prologue (a is NOT folded into the mask term)
  {
    float sa = (t < L_) ? a[t] : 0.f;
#pragma unroll
    for (int off = 1; off < 64; off <<= 1) sa += __shfl_xor(sa, off);
    if (t == 0) sa_l[0] = sa;
    if (t == 64) sa_l[1] = sa;
  }
  __syncthreads();
  const float sum_a = sa_l[0] + sa_l[1];

  float acc[TI];
#pragma unroll
  for (int r = 0; r < TI; ++r) acc[r] = 0.f;

  const float4* __restrict__ xi4 = reinterpret_cast<const float4*>(xi_l);
#pragma unroll 4
  for (int l = 0; l < L_; ++l) {
    const float xj = xs_b[l * N_ + j];  // coalesced 4B/lane
    const float4 xi = xi4[l];           // ds_read_b128, broadcast
    acc[0] += fabsf(xi.x - xj);
    acc[1] += fabsf(xi.y - xj);
    acc[2] += fabsf(xi.z - xj);
    acc[3] += fabsf(xi.w - xj);
  }

  const bool vj = j < bn;
  float val[TI];
#pragma unroll
  for (int r = 0; r < TI; ++r) {
    const bool vi = (i0 + r) < bn;
    const float d = acc[r] - ((vi && vj) ? 0.f : sum_a);  // + mask*sum(a)
    val[r] = d >= 0.f ? d : 0.01f * d;                    // leaky_relu
  }

  const int lane = t & 63;
  const int wid = t >> 6;

  // ---- row max over 512 j ----
  {
    float wm[TI];
#pragma unroll
    for (int r = 0; r < TI; ++r) {
      float m = val[r];
#pragma unroll
      for (int off = 1; off < 64; off <<= 1) m = fmaxf(m, __shfl_xor(m, off));
      wm[r] = m;
    }
    if (lane == 0) {
#pragma unroll
      for (int r = 0; r < TI; ++r) red[wid][r] = wm[r];
    }
  }
  __syncthreads();
  if (t < TI) {
    float m = red[0][t];
#pragma unroll
    for (int w = 1; w < 8; ++w) m = fmaxf(m, red[w][t]);
    rmax_s[t] = m;
  }
  __syncthreads();

  float e[TI];
  const float* __restrict__ adjp = adj + ((size_t)(b * N_ + i0)) * N_ + j;
#pragma unroll
  for (int r = 0; r < TI; ++r) {
    e[r] = adjp[(size_t)r * N_] * expf(val[r] - rmax_s[r]);
  }

  // ---- row sum over 512 j ----
  {
    float wsum[TI];
#pragma unroll
    for (int r = 0; r < TI; ++r) {
      float s = e[r];
#pragma unroll
      for (int off = 1; off < 64; off <<= 1) s += __shfl_xor(s, off);
      wsum[r] = s;
    }
    if (lane == 0) {
#pragma unroll
      for (int r = 0; r < TI; ++r) red[wid][r] = wsum[r];
    }
  }
  __syncthreads();
  if (t < TI) {
    float s = red[0][t];
#pragma unroll
    for (int w = 1; w < 8; ++w) s += red[w][t];
    rsinv_s[t] = 1.0f / s;
  }
  __syncthreads();

  float* __restrict__ op = out + ((size_t)(b * N_ + i0)) * N_ + j;
#pragma unroll
  for (int r = 0; r < TI; ++r) {
    op[(size_t)r * N_] = e[r] * rsinv_s[r] + 1e-10f;
  }
}

}  // namespace

extern "C" void kernel_launch(void* const* d_in, const int* in_sizes, int n_in,
                              void* d_out, int out_size, void* d_ws,
                              size_t ws_size, hipStream_t stream) {
  const float* x = (const float*)d_in[0];    // (B,N,D) f32
  const float* adj = (const float*)d_in[1];  // (B,N,N) f32
  const int* box_num = (const int*)d_in[2];  // (B,1) int32
  const float* W = (const float*)d_in[3];    // (L,D) f32
  const float* a = (const float*)d_in[4];    // (L,) f32
  float* out = (float*)d_out;                // (B,N,N) f32
  float* xs = (float*)d_ws;                  // B*L*N floats = 1 MB scratch

  dim3 g1(L_ / 4, N_ / 128, B_);
  proj_kernel<<<g1, 128, 0, stream>>>(x, W, a, xs);

  dim3 g2(N_ / TI, B_);
  dist_softmax_kernel<<<g2, 512, 0, stream>>>(xs, adj, box_num, a, out);
}